// Round 1
// baseline (641.512 us; speedup 1.0000x reference)
//
#include <hip/hip_runtime.h>

#define NSRC 100000
#define NTGT 50000
#define NE   600000
#define CH   128
#define NREL 7
#define NTYP 4
#define NP   (NREL * NTGT)          // 350000 (rel,dst) pairs
#define NB   ((NP + 1023) / 1024)   // scan blocks (342)
#define MAXBLK ((NTGT + 63) / 64)   // 782

typedef __attribute__((ext_vector_type(4))) float f32x4;
typedef __attribute__((ext_vector_type(8))) short bf16x8;
typedef unsigned int uint;
typedef unsigned short ushort;

static constexpr long long NXB4 = (long long)NSRC * CH / 4;   // 3,200,000
static constexpr long long NXT4 = (long long)NTGT * CH / 4;   // 1,600,000
static constexpr long long NWR4 = (long long)NREL * CH * CH / 4;
static constexpr long long NWT4 = (long long)NTYP * CH * CH / 4;
static constexpr int CONVB  = (int)((NXB4 + NXT4 + NWR4 + NWT4 + 255) / 256); // 18926
static constexpr int COUNTB = (NE + 255) / 256;    // 2344
static constexpr int BUCKETB= (NTGT + 255) / 256;  // 196
static constexpr int INITB  = (NTGT * 32 + 255) / 256; // 6250

// ---- workspace layout ----
static constexpr size_t A256(size_t x) { return (x + 255) & ~(size_t)255; }
static constexpr size_t CNT_O   = 0;                                   // int[NP]
static constexpr size_t TCNT_O  = A256(CNT_O + (size_t)NP * 4);        // int[NTYP]
static constexpr size_t ZERO_END= TCNT_O + 256;                        // memset range
static constexpr size_t BSE_O   = ZERO_END;                            // int[NB]
static constexpr size_t BSR_O   = A256(BSE_O + (size_t)NB * 4);
static constexpr size_t BBE_O   = A256(BSR_O + (size_t)NB * 4);
static constexpr size_t BBR_O   = A256(BBE_O + (size_t)NB * 4);
static constexpr size_t CUR_O   = A256(BBR_O + (size_t)NB * 4);        // int[NP]
static constexpr size_t PLO_O   = A256(CUR_O + (size_t)NP * 4);        // int[NP]
static constexpr size_t PN_O    = A256(PLO_O + (size_t)NP * 4);        // int[NP]
static constexpr size_t PINV_O  = A256(PN_O + (size_t)NP * 4);         // float[NP]
static constexpr size_t PDST_O  = A256(PINV_O + (size_t)NP * 4);       // int[NP]
static constexpr size_t RELO_O  = A256(PDST_O + (size_t)NP * 4);       // int[NREL+1]
static constexpr size_t BKT_O   = A256(RELO_O + 64);                   // int[NTYP*NTGT]
static constexpr size_t SEDGE_O = A256(BKT_O + (size_t)NTYP * NTGT * 4); // int[NE]
static constexpr size_t WB_O    = A256(SEDGE_O + (size_t)NE * 4);      // bf16[11*CH*CH]
static constexpr size_t XB_O    = A256(WB_O + (size_t)(NREL + NTYP) * CH * CH * 2); // bf16[NSRC*CH]
static constexpr size_t XTB_O   = A256(XB_O + (size_t)NSRC * CH * 2);  // bf16[NTGT*CH]
static constexpr size_t PRK_O   = A256(XTB_O + (size_t)NTGT * CH * 2); // int[NP] pair->rank
static constexpr size_t EPAIR_O = A256(PRK_O + (size_t)NP * 4);        // int[NE] edge->rank

__device__ __forceinline__ uint bfpack(float a, float b) {
  uint ua = __float_as_uint(a); ua = (ua + 0x7fff + ((ua >> 16) & 1)) >> 16;
  uint ub = __float_as_uint(b); ub = (ub + 0x7fff + ((ub >> 16) & 1)) >> 16;
  return ua | (ub << 16);
}
__device__ __forceinline__ ushort f2b(float x) {
  uint u = __float_as_uint(x);
  return (ushort)((u + 0x7fff + ((u >> 16) & 1)) >> 16);
}
__device__ __forceinline__ float bl(uint u) { return __uint_as_float(u << 16); }
__device__ __forceinline__ float bh(uint u) { return __uint_as_float(u & 0xffff0000u); }

// ---- fused preprocessing #1: bf16 conversion + (rel,dst) counting + type bucketing ----
__global__ __launch_bounds__(256) void k_pre1(
    const float* __restrict__ xsrc, const float* __restrict__ xt,
    const float* __restrict__ relw, const float* __restrict__ rootw,
    ushort* __restrict__ xb, ushort* __restrict__ xtb, ushort* __restrict__ wb,
    const int* __restrict__ edst, const int* __restrict__ etyp, int* __restrict__ cnt,
    const int* __restrict__ ntyp, int* __restrict__ tcnt, int* __restrict__ bucket) {
  __shared__ int lcnt[NTYP];
  __shared__ int lbase[NTYP];
  int bx = blockIdx.x;
  if (bx < CONVB) {
    long long i4 = (long long)bx * 256 + threadIdx.x;
    const float* src; ushort* dst; long long off;
    if (i4 < NXB4) { src = xsrc; dst = xb; off = i4; }
    else if (i4 < NXB4 + NXT4) { src = xt; dst = xtb; off = i4 - NXB4; }
    else if (i4 < NXB4 + NXT4 + NWR4) { src = relw; dst = wb; off = i4 - NXB4 - NXT4; }
    else if (i4 < NXB4 + NXT4 + NWR4 + NWT4) {
      src = rootw; dst = wb + (size_t)NREL * CH * CH; off = i4 - NXB4 - NXT4 - NWR4;
    } else return;
    float4 v = *(const float4*)(src + off * 4);
    uint lo = (uint)f2b(v.x) | ((uint)f2b(v.y) << 16);
    uint hi = (uint)f2b(v.z) | ((uint)f2b(v.w) << 16);
    uint2 o = make_uint2(lo, hi);
    *(uint2*)(dst + off * 4) = o;
    return;
  }
  bx -= CONVB;
  if (bx < COUNTB) {
    int i = bx * 256 + threadIdx.x;
    if (i < NE) atomicAdd(&cnt[etyp[i] * NTGT + edst[i]], 1);
    return;
  }
  bx -= COUNTB;
  {
    int v = bx * 256 + threadIdx.x;
    if (threadIdx.x < NTYP) lcnt[threadIdx.x] = 0;
    __syncthreads();
    int t = 0, r = 0;
    bool ok = v < NTGT;
    if (ok) { t = ntyp[v]; r = atomicAdd(&lcnt[t], 1); }
    __syncthreads();
    if (threadIdx.x < NTYP) lbase[threadIdx.x] = atomicAdd(&tcnt[threadIdx.x], lcnt[threadIdx.x]);
    __syncthreads();
    if (ok) bucket[t * NTGT + lbase[t] + r] = v;
  }
}

__global__ __launch_bounds__(256) void k_s1(const int* __restrict__ cnt,
                                            int* __restrict__ bsE, int* __restrict__ bsR) {
  __shared__ int sE[256], sR[256];
  int t = threadIdx.x, p0 = blockIdx.x * 1024 + t * 4;
  int e = 0, r = 0;
#pragma unroll
  for (int j = 0; j < 4; ++j) {
    int p = p0 + j;
    if (p < NP) { int c = cnt[p]; e += c; r += (c > 0); }
  }
  sE[t] = e; sR[t] = r; __syncthreads();
  for (int s = 128; s > 0; s >>= 1) {
    if (t < s) { sE[t] += sE[t + s]; sR[t] += sR[t + s]; }
    __syncthreads();
  }
  if (t == 0) { bsE[blockIdx.x] = sE[0]; bsR[blockIdx.x] = sR[0]; }
}

__global__ __launch_bounds__(512) void k_s2(const int* __restrict__ bsE, const int* __restrict__ bsR,
                                            int* __restrict__ bbE, int* __restrict__ bbR,
                                            int* __restrict__ reloff) {
  __shared__ int sE[512], sR[512];
  int t = threadIdx.x;
  int e = (t < NB) ? bsE[t] : 0;
  int r = (t < NB) ? bsR[t] : 0;
  sE[t] = e; sR[t] = r; __syncthreads();
  for (int s = 1; s < 512; s <<= 1) {
    int ae = 0, ar = 0;
    if (t >= s) { ae = sE[t - s]; ar = sR[t - s]; }
    __syncthreads();
    sE[t] += ae; sR[t] += ar;
    __syncthreads();
  }
  if (t < NB) { bbE[t] = sE[t] - e; bbR[t] = sR[t] - r; }
  if (t == NB - 1) reloff[NREL] = sR[t];
}

__global__ __launch_bounds__(256) void k_s3(const int* __restrict__ cnt,
    const int* __restrict__ bbE, const int* __restrict__ bbR,
    int* __restrict__ cur, int* __restrict__ plo, int* __restrict__ pn,
    float* __restrict__ pinv, int* __restrict__ pdst, int* __restrict__ reloff,
    int* __restrict__ prk) {
  __shared__ int sE[256], sR[256];
  int t = threadIdx.x, p0 = blockIdx.x * 1024 + t * 4;
  int c[4]; int e = 0, r = 0;
#pragma unroll
  for (int j = 0; j < 4; ++j) {
    int p = p0 + j;
    c[j] = (p < NP) ? cnt[p] : 0;
    e += c[j]; r += (c[j] > 0);
  }
  sE[t] = e; sR[t] = r; __syncthreads();
  for (int s = 1; s < 256; s <<= 1) {
    int ae = 0, ar = 0;
    if (t >= s) { ae = sE[t - s]; ar = sR[t - s]; }
    __syncthreads();
    sE[t] += ae; sR[t] += ar;
    __syncthreads();
  }
  int baseE = bbE[blockIdx.x] + sE[t] - e;
  int baseR = bbR[blockIdx.x] + sR[t] - r;
#pragma unroll
  for (int j = 0; j < 4; ++j) {
    int p = p0 + j;
    if (p < NP) {
      cur[p] = baseE;
      if ((p % NTGT) == 0) reloff[p / NTGT] = baseR;
      if (c[j] > 0) {
        plo[baseR] = baseE; pn[baseR] = c[j];
        pinv[baseR] = 1.0f / (float)c[j];
        pdst[baseR] = p % NTGT;
        prk[p] = baseR;
        baseR++;
      }
      baseE += c[j];
    }
  }
}

// ---- fused preprocessing #2: edge sort (+rank tag) + bias pre-fill of out ----
__global__ __launch_bounds__(256) void k_pre2(
    const int* __restrict__ esrc, const int* __restrict__ edst,
    const int* __restrict__ etyp, int* __restrict__ cur,
    const int* __restrict__ prk, int* __restrict__ sedge, int* __restrict__ epair,
    const float* __restrict__ rootb, const int* __restrict__ ntyp,
    float* __restrict__ out) {
  int bx = blockIdx.x;
  if (bx < COUNTB) {
    int i = bx * 256 + threadIdx.x;
    if (i < NE) {
      int p = etyp[i] * NTGT + edst[i];
      int pos = atomicAdd(&cur[p], 1);
      sedge[pos] = esrc[i];
      epair[pos] = prk[p];
    }
    return;
  }
  bx -= COUNTB;
  int idx = bx * 256 + threadIdx.x;
  if (idx >= NTGT * 32) return;
  int v = idx >> 5, c4 = (idx & 31) << 2;
  int t = ntyp[v];
  *(float4*)(out + (size_t)v * CH + c4) = *(const float4*)(rootb + (size_t)t * CH + c4);
}

// shared MFMA tail: A from swizzled LDS strip, B from global weights, atomic-add out
__device__ __forceinline__ void mfma_tail(const ushort* strip, const ushort* W,
                                          int m, int quad, const int* rowmap,
                                          float* __restrict__ out) {
  bf16x8 aF[4];
#pragma unroll
  for (int ks = 0; ks < 4; ++ks) {
    int c = ks * 4 + quad;
    aF[ks] = *(const bf16x8*)&strip[(m * 16 + (c ^ m)) << 3];
  }
  f32x4 acc[8];
#pragma unroll
  for (int ct = 0; ct < 8; ++ct) acc[ct] = (f32x4){0.f, 0.f, 0.f, 0.f};
#pragma unroll
  for (int ct = 0; ct < 8; ++ct) {
    int n = ct * 16 + m;
#pragma unroll
    for (int ks = 0; ks < 4; ++ks) {
      bf16x8 bF = *(const bf16x8*)(W + (size_t)n * CH + ks * 32 + quad * 8);
      acc[ct] = __builtin_amdgcn_mfma_f32_16x16x32_bf16(aF[ks], bF, acc[ct], 0, 0, 0);
    }
  }
#pragma unroll
  for (int ct = 0; ct < 8; ++ct)
#pragma unroll
    for (int reg = 0; reg < 4; ++reg)
      if (rowmap[reg] >= 0)
        unsafeAtomicAdd(&out[(size_t)rowmap[reg] * CH + ct * 16 + m], acc[ct][reg]);
}

// single launch: y<NREL -> relation tiles (edge-parallel gather + mean + GEMM),
//                y>=NREL -> root linear
__global__ __launch_bounds__(256) void k_mega(const ushort* __restrict__ xb,
    const ushort* __restrict__ xtb, const ushort* __restrict__ wb,
    const int* __restrict__ plo, const float* __restrict__ pinv,
    const int* __restrict__ pdst, const int* __restrict__ reloff,
    const int* __restrict__ sedge, const int* __restrict__ epair,
    const int* __restrict__ bucket, const int* __restrict__ tcnt,
    float* __restrict__ out) {
  __shared__ float accs[64 * CH];           // 32 KB; low 16 KB reused as MFMA strips
  ushort* As = (ushort*)accs;
  int wv = threadIdx.x >> 6, ln = threadIdx.x & 63;
  ushort* strip = As + wv * (16 * CH);
  int m = ln & 15, quad = ln >> 4;
  int y = blockIdx.y;

  if (y < NREL) {
    int rel = y;
    int base = reloff[rel], relend = reloff[rel + 1];
    int row0 = blockIdx.x * 64;
    if (row0 >= relend - base) return;
    int gr0 = base + row0;
    int gr1 = gr0 + 64; if (gr1 > relend) gr1 = relend;
    int nrtot = reloff[NREL];
    int estart = plo[gr0];
    int eend = (gr1 < nrtot) ? plo[gr1] : NE;

    // zero the f32 accumulator tile
#pragma unroll
    for (int i = 0; i < 32; ++i) accs[threadIdx.x + i * 256] = 0.f;
    __syncthreads();

    // edge-parallel accumulate: batch 32 edges' metadata per wave, broadcast via
    // readlane, fire independent 256B x-row loads into LDS f32 atomics.
    for (int b0 = estart + wv * 32; b0 < eend; b0 += 128) {
      int sv = 0, rv = 0;
      int e = b0 + (ln & 31);
      if (ln < 32 && e < eend) { sv = sedge[e]; rv = epair[e] - gr0; }
      int nb = eend - b0; if (nb > 32) nb = 32;
      if (nb == 32) {
#pragma unroll
        for (int j = 0; j < 32; ++j) {
          int s = __builtin_amdgcn_readlane(sv, j);
          int row = __builtin_amdgcn_readlane(rv, j);
          uint u = *(const uint*)(xb + (size_t)s * CH + (ln << 1));
          atomicAdd(&accs[row * CH + (ln << 1)], bl(u));
          atomicAdd(&accs[row * CH + (ln << 1) + 1], bh(u));
        }
      } else {
        for (int j = 0; j < nb; ++j) {
          int s = __shfl(sv, j);
          int row = __shfl(rv, j);
          uint u = *(const uint*)(xb + (size_t)s * CH + (ln << 1));
          atomicAdd(&accs[row * CH + (ln << 1)], bl(u));
          atomicAdd(&accs[row * CH + (ln << 1) + 1], bh(u));
        }
      }
    }
    __syncthreads();

    // mean + bf16 pack into registers (acc region is about to be overwritten)
    uint wpk[16];
#pragma unroll
    for (int i = 0; i < 16; ++i) {
      int r = wv * 16 + i;
      int gr = gr0 + r;
      float inv = (gr < relend) ? pinv[gr] : 0.f;
      float2 a = *(const float2*)&accs[r * CH + (ln << 1)];
      wpk[i] = bfpack(a.x * inv, a.y * inv);
    }
    __syncthreads();   // all acc reads done before strips overwrite the region
#pragma unroll
    for (int i = 0; i < 16; ++i) {
      int c = ln >> 2;
      *(uint*)&strip[((i * 16 + (c ^ i)) << 3) + ((ln & 3) << 1)] = wpk[i];
    }
    int rowmap[4];
#pragma unroll
    for (int reg = 0; reg < 4; ++reg) {
      int gro = gr0 + wv * 16 + quad * 4 + reg;
      rowmap[reg] = (gro < relend) ? pdst[gro] : -1;
    }
    mfma_tail(strip, wb + (size_t)rel * CH * CH, m, quad, rowmap, out);
  } else {
    int typ = y - NREL;
    int nb = tcnt[typ];
    int row0 = blockIdx.x * 64;
    if (row0 >= nb) return;
    const int* bk = bucket + (size_t)typ * NTGT;
    for (int i = 0; i < 16; ++i) {
      int rr = row0 + wv * 16 + i;
      uint w = 0;
      if (rr < nb) {
        int v = bk[rr];
        w = *(const uint*)(xtb + (size_t)v * CH + (ln << 1));
      }
      int c = ln >> 2;
      *(uint*)&strip[((i * 16 + (c ^ i)) << 3) + ((ln & 3) << 1)] = w;
    }
    int rowmap[4];
#pragma unroll
    for (int reg = 0; reg < 4; ++reg) {
      int rro = row0 + wv * 16 + quad * 4 + reg;
      rowmap[reg] = (rro < nb) ? bk[rro] : -1;
    }
    mfma_tail(strip, wb + (size_t)(NREL + typ) * CH * CH, m, quad, rowmap, out);
  }
}

extern "C" void kernel_launch(void* const* d_in, const int* in_sizes, int n_in,
                              void* d_out, int out_size, void* d_ws, size_t ws_size,
                              hipStream_t stream) {
  (void)in_sizes; (void)n_in; (void)out_size; (void)ws_size;
  const float* xsrc  = (const float*)d_in[0];
  const float* xt    = (const float*)d_in[1];
  const float* relw  = (const float*)d_in[2];
  const float* rootw = (const float*)d_in[3];
  const float* rootb = (const float*)d_in[4];
  const int* esrc = (const int*)d_in[5];
  const int* edst = (const int*)d_in[6];
  const int* etyp = (const int*)d_in[7];
  const int* ntyp = (const int*)d_in[8];
  float* out = (float*)d_out;

  char* ws = (char*)d_ws;
  int*   cnt    = (int*)(ws + CNT_O);
  int*   tcnt   = (int*)(ws + TCNT_O);
  int*   bsE    = (int*)(ws + BSE_O);
  int*   bsR    = (int*)(ws + BSR_O);
  int*   bbE    = (int*)(ws + BBE_O);
  int*   bbR    = (int*)(ws + BBR_O);
  int*   cur    = (int*)(ws + CUR_O);
  int*   plo    = (int*)(ws + PLO_O);
  int*   pn     = (int*)(ws + PN_O);
  float* pinv   = (float*)(ws + PINV_O);
  int*   pdst   = (int*)(ws + PDST_O);
  int*   reloff = (int*)(ws + RELO_O);
  int*   bucket = (int*)(ws + BKT_O);
  int*   sedge  = (int*)(ws + SEDGE_O);
  ushort* wb    = (ushort*)(ws + WB_O);
  ushort* xb    = (ushort*)(ws + XB_O);
  ushort* xtb   = (ushort*)(ws + XTB_O);
  int*   prk    = (int*)(ws + PRK_O);
  int*   epair  = (int*)(ws + EPAIR_O);

  hipMemsetAsync(ws, 0, ZERO_END, stream);
  k_pre1<<<dim3(CONVB + COUNTB + BUCKETB), dim3(256), 0, stream>>>(
      xsrc, xt, relw, rootw, xb, xtb, wb, edst, etyp, cnt, ntyp, tcnt, bucket);
  k_s1<<<dim3(NB), dim3(256), 0, stream>>>(cnt, bsE, bsR);
  k_s2<<<dim3(1), dim3(512), 0, stream>>>(bsE, bsR, bbE, bbR, reloff);
  k_s3<<<dim3(NB), dim3(256), 0, stream>>>(cnt, bbE, bbR, cur, plo, pn, pinv, pdst,
                                           reloff, prk);
  k_pre2<<<dim3(COUNTB + INITB), dim3(256), 0, stream>>>(
      esrc, edst, etyp, cur, prk, sedge, epair, rootb, ntyp, out);
  k_mega<<<dim3(MAXBLK, NREL + NTYP), dim3(256), 0, stream>>>(
      xb, xtb, wb, plo, pinv, pdst, reloff, sedge, epair, bucket, tcnt, out);
}

// Round 2
// 414.917 us; speedup vs baseline: 1.5461x; 1.5461x over previous
//
#include <hip/hip_runtime.h>

#define NSRC 100000
#define NTGT 50000
#define NE   600000
#define CH   128
#define NREL 7
#define NTYP 4
#define NP   (NREL * NTGT)          // 350000 (rel,dst) pairs
#define NB   ((NP + 1023) / 1024)   // scan blocks (342)
#define NBLK ((NTGT + 63) / 64)     // 782 dst tiles

typedef __attribute__((ext_vector_type(4))) float f32x4;
typedef __attribute__((ext_vector_type(8))) short bf16x8;
typedef unsigned int uint;
typedef unsigned short ushort;

static constexpr long long NXB4 = (long long)NSRC * CH / 4;
static constexpr long long NXT4 = (long long)NTGT * CH / 4;
static constexpr long long NWR4 = (long long)NREL * CH * CH / 4;
static constexpr long long NWT4 = (long long)NTYP * CH * CH / 4;
static constexpr int CONVB  = (int)((NXB4 + NXT4 + NWR4 + NWT4 + 255) / 256);
static constexpr int COUNTB = (NE + 255) / 256;

// ---- workspace layout ----
static constexpr size_t A256(size_t x) { return (x + 255) & ~(size_t)255; }
static constexpr size_t CNT_O   = 0;                                   // int[NP] (memset 0)
static constexpr size_t EOFF_O  = A256(CNT_O + (size_t)NP * 4);        // int[NP] excl scan
static constexpr size_t CUR_O   = A256(EOFF_O + (size_t)NP * 4);       // int[NP] sort cursor
static constexpr size_t SEDGE_O = A256(CUR_O + (size_t)NP * 4);        // int[NE] sorted src
static constexpr size_t SDST_O  = A256(SEDGE_O + (size_t)NE * 4);      // int[NE] sorted dst
static constexpr size_t WB_O    = A256(SDST_O + (size_t)NE * 4);       // bf16[11*CH*CH]
static constexpr size_t XB_O    = A256(WB_O + (size_t)(NREL + NTYP) * CH * CH * 2);
static constexpr size_t XTB_O   = A256(XB_O + (size_t)NSRC * CH * 2);  // bf16[NTGT*CH]

__device__ __forceinline__ uint bfpack(float a, float b) {
  uint ua = __float_as_uint(a); ua = (ua + 0x7fff + ((ua >> 16) & 1)) >> 16;
  uint ub = __float_as_uint(b); ub = (ub + 0x7fff + ((ub >> 16) & 1)) >> 16;
  return ua | (ub << 16);
}
__device__ __forceinline__ ushort f2b(float x) {
  uint u = __float_as_uint(x);
  return (ushort)((u + 0x7fff + ((u >> 16) & 1)) >> 16);
}
__device__ __forceinline__ float bl(uint u) { return __uint_as_float(u << 16); }
__device__ __forceinline__ float bh(uint u) { return __uint_as_float(u & 0xffff0000u); }

// ---- fused preprocessing: bf16 conversion + (rel,dst) counting ----
__global__ __launch_bounds__(256) void k_pre1(
    const float* __restrict__ xsrc, const float* __restrict__ xt,
    const float* __restrict__ relw, const float* __restrict__ rootw,
    ushort* __restrict__ xb, ushort* __restrict__ xtb, ushort* __restrict__ wb,
    const int* __restrict__ edst, const int* __restrict__ etyp, int* __restrict__ cnt) {
  int bx = blockIdx.x;
  if (bx < CONVB) {
    long long i4 = (long long)bx * 256 + threadIdx.x;
    const float* src; ushort* dst; long long off;
    if (i4 < NXB4) { src = xsrc; dst = xb; off = i4; }
    else if (i4 < NXB4 + NXT4) { src = xt; dst = xtb; off = i4 - NXB4; }
    else if (i4 < NXB4 + NXT4 + NWR4) { src = relw; dst = wb; off = i4 - NXB4 - NXT4; }
    else if (i4 < NXB4 + NXT4 + NWR4 + NWT4) {
      src = rootw; dst = wb + (size_t)NREL * CH * CH; off = i4 - NXB4 - NXT4 - NWR4;
    } else return;
    float4 v = *(const float4*)(src + off * 4);
    uint lo = (uint)f2b(v.x) | ((uint)f2b(v.y) << 16);
    uint hi = (uint)f2b(v.z) | ((uint)f2b(v.w) << 16);
    uint2 o = make_uint2(lo, hi);
    *(uint2*)(dst + off * 4) = o;
    return;
  }
  bx -= CONVB;
  int i = bx * 256 + threadIdx.x;
  if (i < NE) atomicAdd(&cnt[etyp[i] * NTGT + edst[i]], 1);
}

__global__ __launch_bounds__(256) void k_s1(const int* __restrict__ cnt,
                                            int* __restrict__ bsE) {
  __shared__ int sE[256];
  int t = threadIdx.x, p0 = blockIdx.x * 1024 + t * 4;
  int e = 0;
#pragma unroll
  for (int j = 0; j < 4; ++j) {
    int p = p0 + j;
    if (p < NP) e += cnt[p];
  }
  sE[t] = e; __syncthreads();
  for (int s = 128; s > 0; s >>= 1) {
    if (t < s) sE[t] += sE[t + s];
    __syncthreads();
  }
  if (t == 0) bsE[blockIdx.x] = sE[0];
}

__global__ __launch_bounds__(512) void k_s2(const int* __restrict__ bsE,
                                            int* __restrict__ bbE) {
  __shared__ int sE[512];
  int t = threadIdx.x;
  int e = (t < NB) ? bsE[t] : 0;
  sE[t] = e; __syncthreads();
  for (int s = 1; s < 512; s <<= 1) {
    int ae = 0;
    if (t >= s) ae = sE[t - s];
    __syncthreads();
    sE[t] += ae;
    __syncthreads();
  }
  if (t < NB) bbE[t] = sE[t] - e;
}

__global__ __launch_bounds__(256) void k_s3(const int* __restrict__ cnt,
    const int* __restrict__ bbE, int* __restrict__ eoff, int* __restrict__ cur) {
  __shared__ int sE[256];
  int t = threadIdx.x, p0 = blockIdx.x * 1024 + t * 4;
  int c[4]; int e = 0;
#pragma unroll
  for (int j = 0; j < 4; ++j) {
    int p = p0 + j;
    c[j] = (p < NP) ? cnt[p] : 0;
    e += c[j];
  }
  sE[t] = e; __syncthreads();
  for (int s = 1; s < 256; s <<= 1) {
    int ae = 0;
    if (t >= s) ae = sE[t - s];
    __syncthreads();
    sE[t] += ae;
    __syncthreads();
  }
  int baseE = bbE[blockIdx.x] + sE[t] - e;
#pragma unroll
  for (int j = 0; j < 4; ++j) {
    int p = p0 + j;
    if (p < NP) {
      eoff[p] = baseE;
      cur[p] = baseE;
      baseE += c[j];
    }
  }
}

// edge sort: bucket edges by (rel,dst), record src and dst per slot
__global__ __launch_bounds__(256) void k_esort(
    const int* __restrict__ esrc, const int* __restrict__ edst,
    const int* __restrict__ etyp, int* __restrict__ cur,
    int* __restrict__ sedge, int* __restrict__ sdst) {
  int i = blockIdx.x * 256 + threadIdx.x;
  if (i < NE) {
    int p = etyp[i] * NTGT + edst[i];
    int pos = atomicAdd(&cur[p], 1);
    sedge[pos] = esrc[i];
    sdst[pos] = edst[i];
  }
}

__device__ __forceinline__ void mfma_acc(const ushort* strip, const ushort* W,
                                         int m, int quad, f32x4* acc) {
  bf16x8 aF[4];
#pragma unroll
  for (int ks = 0; ks < 4; ++ks) {
    int c = ks * 4 + quad;
    aF[ks] = *(const bf16x8*)&strip[(m * 16 + (c ^ m)) << 3];
  }
#pragma unroll
  for (int ct = 0; ct < 8; ++ct) {
    int n = ct * 16 + m;
#pragma unroll
    for (int ks = 0; ks < 4; ++ks) {
      bf16x8 bF = *(const bf16x8*)(W + (size_t)n * CH + ks * 32 + quad * 8);
      acc[ct] = __builtin_amdgcn_mfma_f32_16x16x32_bf16(aF[ks], bF, acc[ct], 0, 0, 0);
    }
  }
}

// dst-major mega kernel: each wave owns 16 dst rows; iterates 7 relations +
// 4 root types carrying one MFMA accumulator; single plain store (no atomics).
// All LDS is wave-private -> no __syncthreads anywhere.
__global__ __launch_bounds__(256) void k_mega(const ushort* __restrict__ xb,
    const ushort* __restrict__ xtb, const ushort* __restrict__ wb,
    const int* __restrict__ cnt, const int* __restrict__ eoff,
    const int* __restrict__ sedge, const int* __restrict__ sdst,
    const int* __restrict__ ntyp, const float* __restrict__ rootb,
    float* __restrict__ out) {
  __shared__ float accs[4 * 16 * CH];   // 32 KB, 8 KB per wave
  int wv = threadIdx.x >> 6, ln = threadIdx.x & 63;
  float* accw = accs + wv * (16 * CH);
  ushort* strip = (ushort*)accw;        // bf16 strip overlays acc (wave-private)
  int m = ln & 15, quad = ln >> 4;

  int dstbase = blockIdx.x * 64 + wv * 16;
  if (dstbase >= NTGT) return;          // safe: no block-wide syncs below
  int nvalid = NTGT - dstbase; if (nvalid > 16) nvalid = 16;

  f32x4 acc[8];
#pragma unroll
  for (int ct = 0; ct < 8; ++ct) acc[ct] = (f32x4){0.f, 0.f, 0.f, 0.f};

  // ---- 7 relation phases ----
  for (int rel = 0; rel < NREL; ++rel) {
    int p0 = rel * NTGT + dstbase;
    int pend = p0 + nvalid;
    int e0 = __builtin_amdgcn_readfirstlane(eoff[p0]);
    int e1 = __builtin_amdgcn_readfirstlane((pend < NP) ? eoff[pend] : NE);
    if (e1 <= e0) continue;             // no edges for these 16 dst in this rel

    // zero the wave's f32 accumulator tile (16 x 128)
#pragma unroll
    for (int it = 0; it < 8; ++it)
      *(f32x4*)&accw[it * 256 + (ln << 2)] = (f32x4){0.f, 0.f, 0.f, 0.f};

    // contiguous edge span: prefetch 8 records, 8 independent row loads,
    // then non-atomic LDS f32 RMW (wave-private, DS is in-order per wave)
    int e = e0;
    for (; e + 8 <= e1; e += 8) {
      int s[8], rr[8];
#pragma unroll
      for (int k = 0; k < 8; ++k) {
        s[k] = __builtin_amdgcn_readfirstlane(sedge[e + k]);
        rr[k] = __builtin_amdgcn_readfirstlane(sdst[e + k]) - dstbase;
      }
      uint u[8];
#pragma unroll
      for (int k = 0; k < 8; ++k)
        u[k] = *(const uint*)(xb + (size_t)s[k] * CH + (ln << 1));
#pragma unroll
      for (int k = 0; k < 8; ++k) {
        float* a = &accw[rr[k] * CH + (ln << 1)];
        float2 v = *(float2*)a;
        v.x += bl(u[k]); v.y += bh(u[k]);
        *(float2*)a = v;
      }
    }
    for (; e < e1; ++e) {
      int s = __builtin_amdgcn_readfirstlane(sedge[e]);
      int rr = __builtin_amdgcn_readfirstlane(sdst[e]) - dstbase;
      uint u = *(const uint*)(xb + (size_t)s * CH + (ln << 1));
      float* a = &accw[rr * CH + (ln << 1)];
      float2 v = *(float2*)a;
      v.x += bl(u); v.y += bh(u);
      *(float2*)a = v;
    }

    // mean + bf16 pack via registers, then swizzled strip overwrite
    uint wpk[16];
#pragma unroll
    for (int i = 0; i < 16; ++i) {
      int n = (i < nvalid) ? cnt[p0 + i] : 0;
      float inv = (n > 0) ? __builtin_amdgcn_rcpf((float)n) : 0.f;
      float2 a = *(const float2*)&accw[i * CH + (ln << 1)];
      wpk[i] = bfpack(a.x * inv, a.y * inv);
    }
#pragma unroll
    for (int i = 0; i < 16; ++i) {
      int c = ln >> 2;
      *(uint*)&strip[((i * 16 + (c ^ i)) << 3) + ((ln & 3) << 1)] = wpk[i];
    }
    mfma_acc(strip, wb + (size_t)rel * CH * CH, m, quad, acc);
  }

  // ---- 4 root-type phases (same acc, same rows) ----
  for (int t = 0; t < NTYP; ++t) {
#pragma unroll
    for (int i = 0; i < 16; ++i) {
      int dst = dstbase + i;
      uint w = 0;
      if (i < nvalid && ntyp[dst] == t)
        w = *(const uint*)(xtb + (size_t)dst * CH + (ln << 1));
      int c = ln >> 2;
      *(uint*)&strip[((i * 16 + (c ^ i)) << 3) + ((ln & 3) << 1)] = w;
    }
    mfma_acc(strip, wb + (size_t)(NREL + t) * CH * CH, m, quad, acc);
  }

  // ---- epilogue: add bias, single plain store ----
#pragma unroll
  for (int reg = 0; reg < 4; ++reg) {
    int dst = dstbase + quad * 4 + reg;
    if (dst < NTGT) {
      int t = ntyp[dst];
#pragma unroll
      for (int ct = 0; ct < 8; ++ct) {
        int col = ct * 16 + m;
        out[(size_t)dst * CH + col] = acc[ct][reg] + rootb[(size_t)t * CH + col];
      }
    }
  }
}

extern "C" void kernel_launch(void* const* d_in, const int* in_sizes, int n_in,
                              void* d_out, int out_size, void* d_ws, size_t ws_size,
                              hipStream_t stream) {
  (void)in_sizes; (void)n_in; (void)out_size; (void)ws_size;
  const float* xsrc  = (const float*)d_in[0];
  const float* xt    = (const float*)d_in[1];
  const float* relw  = (const float*)d_in[2];
  const float* rootw = (const float*)d_in[3];
  const float* rootb = (const float*)d_in[4];
  const int* esrc = (const int*)d_in[5];
  const int* edst = (const int*)d_in[6];
  const int* etyp = (const int*)d_in[7];
  const int* ntyp = (const int*)d_in[8];
  float* out = (float*)d_out;

  char* ws = (char*)d_ws;
  int*   cnt    = (int*)(ws + CNT_O);
  int*   eoff   = (int*)(ws + EOFF_O);
  int*   cur    = (int*)(ws + CUR_O);
  int*   sedge  = (int*)(ws + SEDGE_O);
  int*   sdst   = (int*)(ws + SDST_O);
  ushort* wb    = (ushort*)(ws + WB_O);
  ushort* xb    = (ushort*)(ws + XB_O);
  ushort* xtb   = (ushort*)(ws + XTB_O);

  hipMemsetAsync(cnt, 0, (size_t)NP * 4, stream);
  k_pre1<<<dim3(CONVB + COUNTB), dim3(256), 0, stream>>>(
      xsrc, xt, relw, rootw, xb, xtb, wb, edst, etyp, cnt);
  k_s1<<<dim3(NB), dim3(256), 0, stream>>>(cnt, (int*)(ws + EOFF_O));      // bsE in eoff tmp? no
  k_s2<<<dim3(1), dim3(512), 0, stream>>>((int*)(ws + EOFF_O), (int*)(ws + CUR_O));
  k_s3<<<dim3(NB), dim3(256), 0, stream>>>(cnt, (int*)(ws + CUR_O), eoff, cur);
  k_esort<<<dim3(COUNTB), dim3(256), 0, stream>>>(esrc, edst, etyp, cur, sedge, sdst);
  k_mega<<<dim3(NBLK), dim3(256), 0, stream>>>(
      xb, xtb, wb, cnt, eoff, sedge, sdst, ntyp, rootb, out);
}